// Round 10
// baseline (742.188 us; speedup 1.0000x reference)
//
#include <hip/hip_runtime.h>
#include <math.h>

// Problem constants (from reference)
#define N_NODES 40000
#define N_EDGES 640000
#define F_IN    1280
#define H       128
#define NG      64
#define OUTD    273
#define FC1D    1024
#define NEG_SLOPE 0.2f
#define BN_EPS  1e-5f

typedef __attribute__((ext_vector_type(8))) short short8;
typedef __attribute__((ext_vector_type(4))) float f32x4;

__device__ __forceinline__ unsigned short f2bf(float f) {
    unsigned u = __float_as_uint(f);
    u += 0x7FFF + ((u >> 16) & 1);
    return (unsigned short)(u >> 16);
}
__device__ __forceinline__ float bf2f(unsigned short s) {
    return __uint_as_float((unsigned)s << 16);
}

// async global->LDS, 16B per lane (dest = wave-uniform base + lane*16)
__device__ __forceinline__ void gll16(const void* g, void* l) {
    __builtin_amdgcn_global_load_lds(
        (const __attribute__((address_space(1))) unsigned*)g,
        (__attribute__((address_space(3))) unsigned*)l, 16, 0, 0);
}

// ---------------------------------------------------------------------------
// CSR build: histogram -> exclusive scan -> fill  (int4-vectorized edge reads)
// ---------------------------------------------------------------------------
__global__ void edge_hist(const int* __restrict__ dst, int* __restrict__ cnt, int e4) {
    int i = blockIdx.x * blockDim.x + threadIdx.x;
    if (i < e4) {
        int4 d = *(const int4*)(dst + i * 4);
        atomicAdd(&cnt[d.x], 1);
        atomicAdd(&cnt[d.y], 1);
        atomicAdd(&cnt[d.z], 1);
        atomicAdd(&cnt[d.w], 1);
    }
}

__global__ void scan_excl(const int* __restrict__ cnt, int* __restrict__ row_ptr, int n) {
    const int CH = 40;
    __shared__ int sm[1024];
    int tid = threadIdx.x;
    int start = tid * CH;
    int local[CH];
    int s = 0;
    #pragma unroll
    for (int k = 0; k < CH; ++k) {
        int i = start + k;
        int v = (i < n) ? cnt[i] : 0;
        local[k] = s;
        s += v;
    }
    sm[tid] = s;
    __syncthreads();
    for (int off = 1; off < 1024; off <<= 1) {
        int t = (tid >= off) ? sm[tid - off] : 0;
        __syncthreads();
        sm[tid] += t;
        __syncthreads();
    }
    int base = sm[tid] - s;
    #pragma unroll
    for (int k = 0; k < CH; ++k) {
        int i = start + k;
        if (i < n) row_ptr[i] = base + local[k];
    }
    if (tid == 1023) row_ptr[n] = sm[1023];
}

__global__ void edge_fill(const int* __restrict__ src, const int* __restrict__ dst,
                          const int* __restrict__ row_ptr, int* __restrict__ fill,
                          int* __restrict__ csr_src, int e4) {
    int i = blockIdx.x * blockDim.x + threadIdx.x;
    if (i < e4) {
        int4 sv = *(const int4*)(src + i * 4);
        int4 dv = *(const int4*)(dst + i * 4);
        int p;
        p = row_ptr[dv.x] + atomicAdd(&fill[dv.x], 1); csr_src[p] = sv.x;
        p = row_ptr[dv.y] + atomicAdd(&fill[dv.y], 1); csr_src[p] = sv.y;
        p = row_ptr[dv.z] + atomicAdd(&fill[dv.z], 1); csr_src[p] = sv.z;
        p = row_ptr[dv.w] + atomicAdd(&fill[dv.w], 1); csr_src[p] = sv.w;
    }
}

// ---------------------------------------------------------------------------
// weight prep (all 3 layers, one dispatch) + zero row_cnt/fill2 (replaces the
// two hipMemsetAsync dispatches). Layout: chunk-linear bf16 hi/lo (round-5).
// ---------------------------------------------------------------------------
__device__ __forceinline__ void wprep_one(const float* __restrict__ W,
                                          unsigned short* __restrict__ Bp,
                                          int i, int K) {
    int k = i >> 7, col = i & 127;
    float v = W[i];
    unsigned short hh = f2bf(v);
    unsigned short ll = f2bf(v - bf2f(hh));
    int t = k >> 6, rr = k & 63;
    int s = rr >> 5, r5 = rr & 31;
    int laneHi = r5 >> 3, j = r5 & 7;
    int lane = laneHi * 16 + (col & 15);
    int n = col >> 4;
    int U = (n * 2 + s) * 64 + lane;
    size_t idx = (size_t)t * 16384 + (size_t)U * 8 + j;
    Bp[idx] = hh;
    Bp[idx + 8192] = ll;
}

__global__ void wprep_all(const float* __restrict__ W1, const float* __restrict__ W2,
                          const float* __restrict__ W3, unsigned short* __restrict__ Bp1,
                          unsigned short* __restrict__ Bp2, unsigned short* __restrict__ Bp3,
                          int* __restrict__ row_cnt, int* __restrict__ fill2) {
    int i = blockIdx.x * blockDim.x + threadIdx.x;
    if (i < N_NODES) { row_cnt[i] = 0; fill2[i] = 0; }
    const int n1 = F_IN * H, n2 = H * H;
    if (i < n1) { wprep_one(W1, Bp1, i, F_IN); return; }
    int i2 = i - n1;
    if (i2 < n2) { wprep_one(W2, Bp2, i2, H); return; }
    i2 -= n2;
    if (i2 < n2) { wprep_one(W3, Bp3, i2, H); }
}

// ---------------------------------------------------------------------------
// GEMM bf16x3 MFMA v7: h = A @ W + fused scores.
//  - B: global_load_lds (async DMA, 16B/lane) into DOUBLE-buffered LDS (64KB);
//    one __syncthreads per chunk; prefetch loads span the compute phase.
//    (64KB -> 2 blocks/CU, matches the 625-block grid's 2.44 blocks/CU.)
//  - A: fp32 global -> named regs -> hi/lo bf16 (one chunk ahead).
//  nt = K/64 must be even (20, 2: ok).
// ---------------------------------------------------------------------------
__device__ __forceinline__ void cvt8(float4 x, float4 y, short8& hi, short8& lo) {
    float f[8] = {x.x, x.y, x.z, x.w, y.x, y.y, y.z, y.w};
    #pragma unroll
    for (int j = 0; j < 8; ++j) {
        unsigned u = __float_as_uint(f[j]);
        unsigned short hh = (unsigned short)((u + 0x7FFF + ((u >> 16) & 1)) >> 16);
        hi[j] = (short)hh;
        float r = f[j] - __uint_as_float((unsigned)hh << 16);
        unsigned ur = __float_as_uint(r);
        lo[j] = (short)((ur + 0x7FFF + ((ur >> 16) & 1)) >> 16);
    }
}

__global__ __launch_bounds__(256) void gemm_fused(
    const float* __restrict__ A, const unsigned short* __restrict__ Bp,
    const float* __restrict__ a_src, const float* __restrict__ a_dst,
    unsigned short* __restrict__ hWb, float* __restrict__ hs,
    float* __restrict__ hd, int K)
{
    __shared__ __align__(16) unsigned short lds[2][16384];   // 2 x 32 KB
    const int tid  = threadIdx.x;
    const int lane = tid & 63, wv = tid >> 6;
    const int fr = lane & 15, q = lane >> 4;
    const int m0 = blockIdx.x * 64;
    const int row = m0 + wv * 16 + fr;
    const int nt = K >> 6;

    const char* gbB = (const char*)Bp + (size_t)tid * 16;     // per-lane global src
    const size_t ldsWv = (size_t)(tid & ~63) * 16;            // wave-uniform dest base
    const float* Aptr = A + (size_t)row * K + q * 8;

    f32x4 acc0 = {}, acc1 = {}, acc2 = {}, acc3 = {},
          acc4 = {}, acc5 = {}, acc6 = {}, acc7 = {};

    float4 aA0, aA1, aA2, aA3, aB0, aB1, aB2, aB3;

#define GLL(t, buf)                                                             \
    { const char* g = gbB + (size_t)(t) * 32768;                                \
      char* l = (char*)lds[buf] + ldsWv;                                        \
      _Pragma("unroll")                                                         \
      for (int r = 0; r < 8; ++r) gll16(g + r * 4096, l + r * 4096); }
#define LOADA(t, x0, x1, x2, x3)                                                \
    { const float* ap = Aptr + (size_t)(t) * 64;                                \
      x0 = *(const float4*)(ap);      x1 = *(const float4*)(ap + 4);            \
      x2 = *(const float4*)(ap + 32); x3 = *(const float4*)(ap + 36); }
#define MSTEP(buf, nn, accv, ss)                                                \
    { const short8 bh = *(const short8*)&lds[buf][(size_t)(((nn)*2+(ss))*64 + lane)*8];        \
      const short8 bl = *(const short8*)&lds[buf][(size_t)(((nn)*2+(ss))*64 + lane)*8 + 8192]; \
      accv = __builtin_amdgcn_mfma_f32_16x16x32_bf16(ah, bh, accv, 0, 0, 0);    \
      accv = __builtin_amdgcn_mfma_f32_16x16x32_bf16(ah, bl, accv, 0, 0, 0);    \
      accv = __builtin_amdgcn_mfma_f32_16x16x32_bf16(al, bh, accv, 0, 0, 0); }
#define COMPUTE(buf, x0, x1, x2, x3)                                            \
    { short8 ah, al;                                                            \
      cvt8(x0, x1, ah, al);                                                     \
      MSTEP(buf, 0, acc0, 0) MSTEP(buf, 1, acc1, 0) MSTEP(buf, 2, acc2, 0)      \
      MSTEP(buf, 3, acc3, 0) MSTEP(buf, 4, acc4, 0) MSTEP(buf, 5, acc5, 0)      \
      MSTEP(buf, 6, acc6, 0) MSTEP(buf, 7, acc7, 0)                             \
      cvt8(x2, x3, ah, al);                                                     \
      MSTEP(buf, 0, acc0, 1) MSTEP(buf, 1, acc1, 1) MSTEP(buf, 2, acc2, 1)      \
      MSTEP(buf, 3, acc3, 1) MSTEP(buf, 4, acc4, 1) MSTEP(buf, 5, acc5, 1)      \
      MSTEP(buf, 6, acc6, 1) MSTEP(buf, 7, acc7, 1) }

    // prologue: chunk 0 -> buf0, A(0) -> regs
    GLL(0, 0);
    LOADA(0, aA0, aA1, aA2, aA3);
    __syncthreads();                       // implicit vmcnt(0): buf0 ready

    for (int t = 0; t < nt; t += 2) {
        // issue chunk t+1 into buf1 while computing buf0
        GLL(t + 1, 1);
        LOADA(t + 1, aB0, aB1, aB2, aB3);
        COMPUTE(0, aA0, aA1, aA2, aA3);
        __syncthreads();                   // drains t+1 loads (had full compute to land)

        if (t + 2 < nt) {
            GLL(t + 2, 0);
            LOADA(t + 2, aA0, aA1, aA2, aA3);
        }
        COMPUTE(1, aB0, aB1, aB2, aB3);
        __syncthreads();
    }
#undef GLL
#undef LOADA
#undef MSTEP
#undef COMPUTE

    // epilogue 1: bf16 h store. C/D layout col=lane&15, row=(lane>>4)*4+i
    const int rb = m0 + wv * 16 + q * 4;
#define EPI(nn, accv)                                                           \
    {                                                                           \
        _Pragma("unroll")                                                       \
        for (int i = 0; i < 4; ++i)                                             \
            hWb[(size_t)(rb + i) * H + (nn)*16 + fr] = f2bf(accv[i]);           \
    }
    EPI(0, acc0) EPI(1, acc1) EPI(2, acc2) EPI(3, acc3)
    EPI(4, acc4) EPI(5, acc5) EPI(6, acc6) EPI(7, acc7)
#undef EPI

    // epilogue 2: fused scores hs/hd from fp32 acc
    float asv[8], adv[8];
    #pragma unroll
    for (int n = 0; n < 8; ++n) {
        asv[n] = a_src[n * 16 + fr];
        adv[n] = a_dst[n * 16 + fr];
    }
    #pragma unroll
    for (int i = 0; i < 4; ++i) {
        float ss = acc0[i]*asv[0] + acc1[i]*asv[1] + acc2[i]*asv[2] + acc3[i]*asv[3]
                 + acc4[i]*asv[4] + acc5[i]*asv[5] + acc6[i]*asv[6] + acc7[i]*asv[7];
        float dd = acc0[i]*adv[0] + acc1[i]*adv[1] + acc2[i]*adv[2] + acc3[i]*adv[3]
                 + acc4[i]*adv[4] + acc5[i]*adv[5] + acc6[i]*adv[6] + acc7[i]*adv[7];
        #pragma unroll
        for (int off = 8; off; off >>= 1) {
            ss += __shfl_xor(ss, off);
            dd += __shfl_xor(dd, off);
        }
        if (fr == 0) { hs[rb + i] = ss; hd[rb + i] = dd; }
    }
}

// ---------------------------------------------------------------------------
// fused segment softmax + aggregation, one wave per dst node (round-9 version:
// dependent hs load first, 16 gathers in flight across the softmax).
// ---------------------------------------------------------------------------
__device__ __forceinline__ float bfhi(unsigned u) { return __uint_as_float(u << 16); }
__device__ __forceinline__ float bflo(unsigned u) { return __uint_as_float(u & 0xffff0000u); }

__global__ void attn_agg(const unsigned short* __restrict__ hWb,
                         const float* __restrict__ hs, const float* __restrict__ hd,
                         const int* __restrict__ row_ptr, const int* __restrict__ csr_src,
                         const float* __restrict__ bias, float* __restrict__ out,
                         int n, int relu_flag) {
    int wv = (blockIdx.x * blockDim.x + threadIdx.x) >> 6;
    int lane = threadIdx.x & 63;
    if (wv >= n) return;
    int p0 = row_ptr[wv], p1 = row_ptr[wv + 1];
    int deg = p1 - p0;
    float hdi = hd[wv];
    float ax = 0.f, ay = 0.f;
    const unsigned* hb = (const unsigned*)hWb;

    if (deg <= 64) {
        int valid = (lane < deg);
        int sidx = valid ? csr_src[p0 + lane] : 0;
        float hsv = hs[sidx];                      // dependent load first

#define PF(k) int s_##k = __shfl(sidx, k); unsigned u_##k = 0;                  \
              if (deg > k) u_##k = hb[(size_t)s_##k * 64 + lane];
        PF(0)  PF(1)  PF(2)  PF(3)  PF(4)  PF(5)  PF(6)  PF(7)
        PF(8)  PF(9)  PF(10) PF(11) PF(12) PF(13) PF(14) PF(15)
#undef PF

        float e = hsv + hdi;
        e = (e >= 0.f) ? e : NEG_SLOPE * e;
        float m = valid ? e : -3.4e38f;
        #pragma unroll
        for (int off = 32; off; off >>= 1) m = fmaxf(m, __shfl_xor(m, off));
        float pe = valid ? __expf(e - m) : 0.f;
        float dsum = pe;
        #pragma unroll
        for (int off = 32; off; off >>= 1) dsum += __shfl_xor(dsum, off);
        pe *= 1.f / (dsum + 1e-16f);

#define AC(k) if (deg > k) { float aa = __shfl(pe, k);                          \
                             ax += aa * bfhi(u_##k); ay += aa * bflo(u_##k); }
        AC(0)  AC(1)  AC(2)  AC(3)  AC(4)  AC(5)  AC(6)  AC(7)
        AC(8)  AC(9)  AC(10) AC(11) AC(12) AC(13) AC(14) AC(15)
#undef AC

        for (int j = 16; j < deg; j += 4) {
            int t0 = __shfl(sidx, j);
            int t1 = (j + 1 < deg) ? __shfl(sidx, j + 1) : t0;
            int t2 = (j + 2 < deg) ? __shfl(sidx, j + 2) : t0;
            int t3 = (j + 3 < deg) ? __shfl(sidx, j + 3) : t0;
            unsigned v0 = hb[(size_t)t0 * 64 + lane];
            unsigned v1 = hb[(size_t)t1 * 64 + lane];
            unsigned v2 = hb[(size_t)t2 * 64 + lane];
            unsigned v3 = hb[(size_t)t3 * 64 + lane];
            float b0 = __shfl(pe, j);
            float b1 = (j + 1 < deg) ? __shfl(pe, j + 1) : 0.f;
            float b2 = (j + 2 < deg) ? __shfl(pe, j + 2) : 0.f;
            float b3 = (j + 3 < deg) ? __shfl(pe, j + 3) : 0.f;
            ax += b0 * bfhi(v0); ay += b0 * bflo(v0);
            ax += b1 * bfhi(v1); ay += b1 * bflo(v1);
            ax += b2 * bfhi(v2); ay += b2 * bflo(v2);
            ax += b3 * bfhi(v3); ay += b3 * bflo(v3);
        }
    } else {
        float m = -3.4e38f;
        for (int p = p0 + lane; p < p1; p += 64) {
            float e = hs[csr_src[p]] + hdi;
            e = (e >= 0.f) ? e : NEG_SLOPE * e;
            m = fmaxf(m, e);
        }
        #pragma unroll
        for (int off = 32; off; off >>= 1) m = fmaxf(m, __shfl_xor(m, off));
        float dsum = 0.f;
        for (int p = p0 + lane; p < p1; p += 64) {
            float e = hs[csr_src[p]] + hdi;
            e = (e >= 0.f) ? e : NEG_SLOPE * e;
            dsum += __expf(e - m);
        }
        #pragma unroll
        for (int off = 32; off; off >>= 1) dsum += __shfl_xor(dsum, off);
        float inv = 1.f / (dsum + 1e-16f);
        for (int p = p0; p < p1; ++p) {
            int s = csr_src[p];
            float e = hs[s] + hdi;
            e = (e >= 0.f) ? e : NEG_SLOPE * e;
            float alpha = __expf(e - m) * inv;
            unsigned u = hb[(size_t)s * 64 + lane];
            ax += alpha * bfhi(u); ay += alpha * bflo(u);
        }
    }
    float2 bv = *(const float2*)&bias[2 * lane];
    float o0 = ax + bv.x;
    float o1 = ay + bv.y;
    if (relu_flag) { o0 = fmaxf(o0, 0.f); o1 = fmaxf(o1, 0.f); }
    float2 ov; ov.x = o0; ov.y = o1;
    *(float2*)&out[(size_t)wv * H + 2 * lane] = ov;
}

// ---------------------------------------------------------------------------
// global mean pool, stage 1: per-graph 8-way partial sums
// ---------------------------------------------------------------------------
__device__ __forceinline__ void graph_range(const int* __restrict__ batch, int n,
                                            int g, int& start, int& end) {
    int lo = 0, hi = n;
    while (lo < hi) { int mid = (lo + hi) >> 1; if (batch[mid] < g) lo = mid + 1; else hi = mid; }
    start = lo;
    lo = start; hi = n;
    while (lo < hi) { int mid = (lo + hi) >> 1; if (batch[mid] < g + 1) lo = mid + 1; else hi = mid; }
    end = lo;
}

__global__ void pool_part(const float* __restrict__ h, const int* __restrict__ batch,
                          float* __restrict__ part, int n) {
    int g = blockIdx.x >> 3, c = blockIdx.x & 7;
    int f = threadIdx.x;
    int start, end;
    graph_range(batch, n, g, start, end);
    int len = end - start;
    int cs = start + (len * c) / 8, ce = start + (len * (c + 1)) / 8;
    float acc = 0.f;
    for (int i = cs; i < ce; ++i) acc += h[(size_t)i * H + f];
    part[((size_t)g * 8 + c) * H + f] = acc;
}

// ---------------------------------------------------------------------------
// pool finish + FC1 + BN(eval) + ReLU fused : z[64][1024]
// ---------------------------------------------------------------------------
__global__ void fc1_bn_relu(const float* __restrict__ part, const int* __restrict__ batch,
                            const float* __restrict__ W, const float* __restrict__ b,
                            const float* __restrict__ bng, const float* __restrict__ bnb,
                            const float* __restrict__ bnrm, const float* __restrict__ bnrv,
                            float* __restrict__ z, int n) {
    __shared__ float pr[H];
    int g = blockIdx.x >> 2;
    int tid = threadIdx.x;
    if (tid < H) {
        int start, end;
        graph_range(batch, n, g, start, end);
        float s = 0.f;
        #pragma unroll
        for (int c = 0; c < 8; ++c) s += part[((size_t)g * 8 + c) * H + tid];
        pr[tid] = s / fmaxf((float)(end - start), 1.f);
    }
    __syncthreads();
    int j = ((blockIdx.x & 3) << 8) + tid;
    float acc = b[j];
    #pragma unroll 8
    for (int k = 0; k < H; ++k) acc += pr[k] * W[k * FC1D + j];
    float v = (acc - bnrm[j]) * rsqrtf(bnrv[j] + BN_EPS) * bng[j] + bnb[j];
    z[g * FC1D + j] = fmaxf(v, 0.f);
}

// ---------------------------------------------------------------------------
// FC2 + sigmoid : out[64][273]
// ---------------------------------------------------------------------------
__global__ void fc2_sig(const float* __restrict__ z, const float* __restrict__ W,
                        const float* __restrict__ b, float* __restrict__ out) {
    int g = blockIdx.x;
    int j = threadIdx.x;
    if (j >= OUTD) return;
    const float* zr = z + g * FC1D;
    float acc = b[j];
    #pragma unroll 4
    for (int k = 0; k < FC1D; ++k) acc += zr[k] * W[k * OUTD + j];
    out[g * OUTD + j] = 1.f / (1.f + __expf(-acc));
}

// ---------------------------------------------------------------------------
extern "C" void kernel_launch(void* const* d_in, const int* in_sizes, int n_in,
                              void* d_out, int out_size, void* d_ws, size_t ws_size,
                              hipStream_t stream) {
    const float* x     = (const float*)d_in[0];
    const int*   eidx  = (const int*)d_in[1];
    const int*   batch = (const int*)d_in[2];
    const float* W1 = (const float*)d_in[3];  const float* b1 = (const float*)d_in[4];
    const float* as1 = (const float*)d_in[5]; const float* ad1 = (const float*)d_in[6];
    const float* W2 = (const float*)d_in[7];  const float* b2 = (const float*)d_in[8];
    const float* as2 = (const float*)d_in[9]; const float* ad2 = (const float*)d_in[10];
    const float* W3 = (const float*)d_in[11]; const float* b3 = (const float*)d_in[12];
    const float* as3 = (const float*)d_in[13]; const float* ad3 = (const float*)d_in[14];
    const float* fc1W = (const float*)d_in[15]; const float* fc1b = (const float*)d_in[16];
    const float* bng = (const float*)d_in[17];  const float* bnb = (const float*)d_in[18];
    const float* bnrm = (const float*)d_in[19]; const float* bnrv = (const float*)d_in[20];
    const float* fc2W = (const float*)d_in[21]; const float* fc2b = (const float*)d_in[22];
    const int* src = eidx;
    const int* dst = eidx + N_EDGES;

    // workspace layout
    float* hA      = (float*)d_ws;                     // N*H fp32
    float* hs      = hA + (size_t)N_NODES * H;         // N
    float* hd      = hs + N_NODES;                     // N
    float* part    = hd + N_NODES;                     // G*8*H
    float* z       = part + NG * 8 * H;                // G*1024
    unsigned short* hWb = (unsigned short*)(z + NG * FC1D);    // N*H bf16
    unsigned short* Bp1 = hWb + (size_t)N_NODES * H;           // 20 chunks * 16384
    unsigned short* Bp2 = Bp1 + (size_t)(F_IN / 64) * 16384;   // 2 chunks
    unsigned short* Bp3 = Bp2 + (size_t)(H / 64) * 16384;      // 2 chunks
    int*   row_ptr = (int*)(Bp3 + (size_t)(H / 64) * 16384);   // N+1
    int*   row_cnt = row_ptr + (N_NODES + 1);          // N
    int*   csr_src = row_cnt + N_NODES;                // E
    int*   fill2   = csr_src + N_EDGES;                // N

    const int E4 = N_EDGES / 4;
    const int EB = (E4 + 255) / 256;
    const int NW = (N_NODES * 64 + 255) / 256;
    const int GB = N_NODES / 64;

    // ---- weight prep + zero counters (one dispatch) ----
    const int WTOT = F_IN * H + 2 * H * H;
    wprep_all<<<(WTOT + 255) / 256, 256, 0, stream>>>(W1, W2, W3, Bp1, Bp2, Bp3,
                                                      row_cnt, fill2);

    // ---- CSR build (by dst) ----
    edge_hist<<<EB, 256, 0, stream>>>(dst, row_cnt, E4);
    scan_excl<<<1, 1024, 0, stream>>>(row_cnt, row_ptr, N_NODES);
    edge_fill<<<EB, 256, 0, stream>>>(src, dst, row_ptr, fill2, csr_src, E4);

    // ---- layer 1 ----
    gemm_fused<<<GB, 256, 0, stream>>>(x, Bp1, as1, ad1, hWb, hs, hd, F_IN);
    attn_agg<<<NW, 256, 0, stream>>>(hWb, hs, hd, row_ptr, csr_src, b1, hA, N_NODES, 1);
    // ---- layer 2 ----
    gemm_fused<<<GB, 256, 0, stream>>>(hA, Bp2, as2, ad2, hWb, hs, hd, H);
    attn_agg<<<NW, 256, 0, stream>>>(hWb, hs, hd, row_ptr, csr_src, b2, hA, N_NODES, 1);
    // ---- layer 3 (no relu) ----
    gemm_fused<<<GB, 256, 0, stream>>>(hA, Bp3, as3, ad3, hWb, hs, hd, H);
    attn_agg<<<NW, 256, 0, stream>>>(hWb, hs, hd, row_ptr, csr_src, b3, hA, N_NODES, 0);

    // ---- head ----
    pool_part<<<NG * 8, H, 0, stream>>>(hA, batch, part, N_NODES);
    fc1_bn_relu<<<NG * 4, 256, 0, stream>>>(part, batch, fc1W, fc1b, bng, bnb, bnrm, bnrv, z, N_NODES);
    fc2_sig<<<NG, 320, 0, stream>>>(z, fc2W, fc2b, (float*)d_out);
}